// Round 11
// baseline (574.870 us; speedup 1.0000x reference)
//
#include <hip/hip_runtime.h>
#include <hip/hip_cooperative_groups.h>
namespace cg = cooperative_groups;

// ---------------------------------------------------------------------------
// GCN model, re-associated. R11: ONE cooperative mega-kernel (init -> bin ->
// csr -> L0 -> L1 -> L2+pool -> head) with grid.sync between phases.
// History: R3 ping-pong fusion 338; R7 spill-free 4-wide gather 326;
// R9 LDS-ids 320.8 (best); R10 L2-window-sort null (FETCH 77->75, dur same).
// Budget analysis: total - 3*k_fused ~= 160us every round; k_csr<=50,
// bin~15, init~5, head~5 => ~80-90us of inter-dispatch gaps (7 x ~12us).
// R11 eliminates 6 gaps for ~6 grid-syncs. Phase logic is bit-identical R9
// (bin slice reverted to blockIdx-based; R10's src-slice was null + contended).
// Proven constraints kept: (1024,8)=2blk/CU, 64-VGPR budget, 4-wide gather
// (8-wide spills: R6/R8), LDS ids, x8-padded edges, dummy row N.
// ---------------------------------------------------------------------------

typedef __attribute__((ext_vector_type(8))) short short8;   // MFMA A/B frag
typedef __attribute__((ext_vector_type(4))) float f32x4;    // MFMA C/D frag

#define BKT 64        // nodes per bucket
#define SL 16         // slices per bucket
#define CAP 192       // capacity per (bucket,slice) cell   (Poisson 64)
#define WCAP 2560     // csrf window per bucket (padded degs; Poisson 1024)
#define HROWS 65536   // h-buffer rows allocated (row N = dummy zero row)

// Head-weight bf16 arena offsets (elements)
#define HW_MLP0 0
#define HW_MLP1 65536
#define HW_MLO  131072
#define HW_GCNO 147456
#define HW_PW1  163840
#define HW_PW2  212992
#define HW_TOT  278528

__device__ __forceinline__ unsigned short f2bf(float f) {
    union { float f; unsigned u; } c; c.f = f;
    unsigned u = c.u;
    unsigned r = u + 0x7FFFu + ((u >> 16) & 1u);   // RNE
    return (unsigned short)(r >> 16);
}
__device__ __forceinline__ float bflo(unsigned w) {
    union { unsigned u; float f; } c; c.u = w << 16; return c.f;
}
__device__ __forceinline__ float bfhi(unsigned w) {
    union { unsigned u; float f; } c; c.u = w & 0xFFFF0000u; return c.f;
}

struct MegaParams {
    int* cur; float* pool; float* cnt;
    const float* gcnW; uint4* Wb;
    const float* mlpW; const float* mloW; const float* gcnoW;
    const float* pW1; const float* pW2; unsigned short* Wh;
    unsigned short* xb; unsigned short* bufA; unsigned short* bufB;
    const int* batch; const int* row; const int* col;
    unsigned* gbin;
    int* rs; unsigned short* rd; float* dinv; unsigned short* csrf;
    const float* x; const float* gcnb;
    const float* mol; const float* mlpb; const float* mlob; const float* gcnob;
    const float* pb1; const float* pb2; const float* oW; const float* ob;
    float* out;
    int M, G, N, E, NBK;
};

__global__ __launch_bounds__(1024, 8) void k_mega(MegaParams p) {
    cg::grid_group gg = cg::this_grid();
    const int t = threadIdx.x;
    const int nb = gridDim.x;

    union SMem {
        struct { uint4 Wsh[2048]; unsigned short Ash[64][136];
                 unsigned short Ish[WCAP]; } f;                       // 55296 B
        struct { int hcnt[64]; int lcur[64]; int fills[SL];
                 float sdinv[64]; } c;
        struct { unsigned short A[16][264]; unsigned short Bs[16][264];
                 unsigned short Cc[16][200]; unsigned short Mn[16][136];
                 float red[4][16]; } h;
    };
    __shared__ SMem sm;

    // ================= phase 0: init =================
    {
        const int itot = p.M * 16;    // dominates all sub-ranges
        for (int i = blockIdx.x * 1024 + t; i < itot; i += nb * 1024) {
            p.cur[i] = 0;
            if (i < p.G * 128) p.pool[i] = 0.f;
            if (i < p.G) {
                int lo = 0, hi = p.N;
                while (lo < hi) { int m = (lo + hi) >> 1; if (p.batch[m] < i) lo = m + 1; else hi = m; }
                int lo2 = lo, hi2 = p.N;
                while (lo2 < hi2) { int m = (lo2 + hi2) >> 1; if (p.batch[m] < i + 1) lo2 = m + 1; else hi2 = m; }
                p.cnt[i] = (float)(lo2 - lo);
            }
            if (i < 192) {                   // zero dummy row N of 3 h-buffers
                unsigned short* b = (i < 64) ? p.xb : (i < 128) ? p.bufA : p.bufB;
                *(unsigned*)(b + (size_t)p.N * 128 + (i & 63) * 2) = 0u;
            }
            if (i < 3 * 2048) {              // gcn W cast (swizzled)
                int l = i >> 11, rem = i & 2047;
                int o = rem >> 4, c = rem & 15;
                const float4* s = (const float4*)(p.gcnW + (size_t)l * 16384 + o * 128 + c * 8);
                float4 a = s[0], b = s[1];
                uint4 v;
                v.x = ((unsigned)f2bf(a.y) << 16) | f2bf(a.x);
                v.y = ((unsigned)f2bf(a.w) << 16) | f2bf(a.z);
                v.z = ((unsigned)f2bf(b.y) << 16) | f2bf(b.x);
                v.w = ((unsigned)f2bf(b.w) << 16) | f2bf(b.z);
                p.Wb[(l << 11) | (o << 4) | (c ^ (o & 15))] = v;
            }
            int j = i - 8192;                // head-weight flat cast
            if (j >= 0 && j < (HW_TOT / 8)) {
                int e = j * 8;
                const float* src;
                if (e < HW_MLO)        src = p.mlpW  + e;
                else if (e < HW_GCNO)  src = p.mloW  + (e - HW_MLO);
                else if (e < HW_PW1)   src = p.gcnoW + (e - HW_GCNO);
                else if (e < HW_PW2)   src = p.pW1   + (e - HW_PW1);
                else                   src = p.pW2   + (e - HW_PW2);
                float4 a = *(const float4*)src;
                float4 b = *((const float4*)src + 1);
                uint4 v;
                v.x = ((unsigned)f2bf(a.y) << 16) | f2bf(a.x);
                v.y = ((unsigned)f2bf(a.w) << 16) | f2bf(a.z);
                v.z = ((unsigned)f2bf(b.y) << 16) | f2bf(b.x);
                v.w = ((unsigned)f2bf(b.w) << 16) | f2bf(b.z);
                *(uint4*)(p.Wh + e) = v;
            }
        }
    }
    gg.sync();

    // ================= phase 1: bin =================
    {
        const int x = blockIdx.x & (SL - 1);
        for (int e = blockIdx.x * 1024 + t; e < p.E; e += nb * 1024) {
            int c = p.col[e];
            int cell = (c >> 6) * SL + x;
            int cnt = atomicAdd(&p.cur[cell << 4], 1);
            p.gbin[cell * CAP + cnt] = (unsigned)p.row[e] | ((unsigned)(c & 63) << 16);
        }
    }
    gg.sync();

    // ================= phase 2: csr =================
    for (int b = blockIdx.x; b < p.NBK; b += nb) {
        if (t < 64) sm.c.hcnt[t] = 0;
        if (t < SL) sm.c.fills[t] = p.cur[(b * SL + t) << 4];
        __syncthreads();
        for (int xx = 0; xx < SL; ++xx) {
            int cbase = (b * SL + xx) * CAP, fill = sm.c.fills[xx];
            for (int i = t; i < fill; i += 1024)
                atomicAdd(&sm.c.hcnt[(p.gbin[cbase + i] >> 16) & 63], 1);
        }
        __syncthreads();
        if (t < 64) {
            int v = sm.c.hcnt[t];
            int vp = (v + 7) & ~7;
            int xs = vp;
            #pragma unroll
            for (int off = 1; off < 64; off <<= 1) {
                int u = __shfl_up(xs, off, 64);
                if (t >= off) xs += u;
            }
            int excl = xs - vp;
            sm.c.lcur[t] = excl;
            float d = rsqrtf((float)v + 1.0f);
            sm.c.sdinv[t] = d;
            int node = b * 64 + t;
            p.rs[node] = b * WCAP + excl;
            p.rd[node] = (unsigned short)v;
            p.dinv[node] = d;
        }
        __syncthreads();
        for (int xx = 0; xx < SL; ++xx) {
            int cbase = (b * SL + xx) * CAP, fill = sm.c.fills[xx];
            for (int i = t; i < fill; i += 1024) {
                unsigned v = p.gbin[cbase + i];
                int pp = atomicAdd(&sm.c.lcur[(v >> 16) & 63], 1);
                p.csrf[b * WCAP + pp] = (unsigned short)(v & 0xFFFFu);
            }
        }
        __syncthreads();
        if (t < 64) {                        // pad with dummy src N
            int v = sm.c.hcnt[t], vp = (v + 7) & ~7;
            int base = sm.c.lcur[t];
            for (int q = v; q < vp; ++q)
                p.csrf[b * WCAP + base + (q - v)] = (unsigned short)p.N;
        }
        {   // fused x -> bf16*dinv cast: 1024 thr = 64 nodes x 16 chunks
            int nd = b * 64 + (t >> 4);
            if (nd < p.N) {
                int ch = t & 15;
                float d = sm.c.sdinv[t >> 4];
                const float4* s = (const float4*)(p.x + (size_t)nd * 128 + ch * 8);
                float4 a = s[0], bb = s[1];
                uint4 o;
                o.x = ((unsigned)f2bf(d * a.y) << 16) | f2bf(d * a.x);
                o.y = ((unsigned)f2bf(d * a.w) << 16) | f2bf(d * a.z);
                o.z = ((unsigned)f2bf(d * bb.y) << 16) | f2bf(d * bb.x);
                o.w = ((unsigned)f2bf(d * bb.w) << 16) | f2bf(d * bb.z);
                *(uint4*)(p.xb + (size_t)nd * 128 + ch * 8) = o;
            }
        }
        __syncthreads();
    }
    gg.sync();

    // ================= phases 3-5: GCN layers =================
    {
        const int sub = t >> 4;
        const int fg = t & 15;
        const unsigned fgo = (unsigned)fg * 8u;
        const int fblocks = (p.N + 63) / 64;
        for (int l = 0; l < 3; ++l) {
            const unsigned short* h = (l == 0) ? p.xb : (l == 1) ? p.bufA : p.bufB;
            unsigned short* Cd = (l == 0) ? p.bufA : p.bufB;
            const float* dscale = (l < 2) ? p.dinv : (const float*)nullptr;
            float* pl = (l == 2) ? p.pool : (float*)nullptr;
            const float* bias = p.gcnb + l * 128;
            const uint4* Wbl = p.Wb + l * 2048;
            sm.f.Wsh[t] = Wbl[t];
            sm.f.Wsh[t + 1024] = Wbl[t + 1024];

            for (int tile = blockIdx.x; tile < fblocks; tile += nb) {
                __syncthreads();     // prev tile MFMA done; Wsh visible
                const int blk0 = tile * 64;
                const int node = blk0 + sub;
                const int base = tile * WCAP;
                const int ln = blk0 + 63;
                const int wcnt = (p.rs[ln] + ((p.rd[ln] + 7) & ~7)) - base;
                for (int i = t * 8; i < wcnt; i += 8192)
                    *(uint4*)(&sm.f.Ish[i]) = *(const uint4*)(p.csrf + base + i);
                __syncthreads();

                // ---- gather: 4-wide, ids from LDS ----
                float acc[8] = {0.f, 0.f, 0.f, 0.f, 0.f, 0.f, 0.f, 0.f};
                if (node < p.N) {
                    uint4 hv = *(const uint4*)(h + (size_t)node * 128u + fgo);
                    acc[0] = bflo(hv.x); acc[1] = bfhi(hv.x);
                    acc[2] = bflo(hv.y); acc[3] = bfhi(hv.y);
                    acc[4] = bflo(hv.z); acc[5] = bfhi(hv.z);
                    acc[6] = bflo(hv.w); acc[7] = bfhi(hv.w);
                }
                {
                    const int stl = p.rs[node] - base;
                    const int epl = stl + ((p.rd[node] + 7) & ~7);
                    #pragma unroll 1
                    for (int i = stl; i < epl; i += 4) {
                        const uint2 iv = *(const uint2*)(&sm.f.Ish[i]);
                        const uint4 v0 = *(const uint4*)(h + ((iv.x & 0xFFFFu) * 128u + fgo));
                        const uint4 v1 = *(const uint4*)(h + ((iv.x >> 16)     * 128u + fgo));
                        const uint4 v2 = *(const uint4*)(h + ((iv.y & 0xFFFFu) * 128u + fgo));
                        const uint4 v3 = *(const uint4*)(h + ((iv.y >> 16)     * 128u + fgo));
                        acc[0] += bflo(v0.x); acc[1] += bfhi(v0.x);
                        acc[2] += bflo(v0.y); acc[3] += bfhi(v0.y);
                        acc[4] += bflo(v0.z); acc[5] += bfhi(v0.z);
                        acc[6] += bflo(v0.w); acc[7] += bfhi(v0.w);
                        acc[0] += bflo(v1.x); acc[1] += bfhi(v1.x);
                        acc[2] += bflo(v1.y); acc[3] += bfhi(v1.y);
                        acc[4] += bflo(v1.z); acc[5] += bfhi(v1.z);
                        acc[6] += bflo(v1.w); acc[7] += bfhi(v1.w);
                        acc[0] += bflo(v2.x); acc[1] += bfhi(v2.x);
                        acc[2] += bflo(v2.y); acc[3] += bfhi(v2.y);
                        acc[4] += bflo(v2.z); acc[5] += bfhi(v2.z);
                        acc[6] += bflo(v2.w); acc[7] += bfhi(v2.w);
                        acc[0] += bflo(v3.x); acc[1] += bfhi(v3.x);
                        acc[2] += bflo(v3.y); acc[3] += bfhi(v3.y);
                        acc[4] += bflo(v3.z); acc[5] += bfhi(v3.z);
                        acc[6] += bflo(v3.w); acc[7] += bfhi(v3.w);
                    }
                }
                {   // scale + pack to bf16 A-tile
                    const float dn = (node < p.N) ? p.dinv[node] : 0.f;
                    unsigned short ob[8];
                    #pragma unroll
                    for (int j = 0; j < 8; ++j) ob[j] = f2bf(acc[j] * dn);
                    uint4 o;
                    o.x = ((unsigned)ob[1] << 16) | ob[0];
                    o.y = ((unsigned)ob[3] << 16) | ob[2];
                    o.z = ((unsigned)ob[5] << 16) | ob[4];
                    o.w = ((unsigned)ob[7] << 16) | ob[6];
                    *(uint4*)(&sm.f.Ash[sub][fg * 8]) = o;
                }
                __syncthreads();

                // ---- MFMA ----
                const int lane = t & 63;
                const int wv = t >> 6;
                const int l15 = lane & 15, quad = lane >> 4;
                const int rt = wv & 3, cp = wv >> 2;
                f32x4 acc2[2];
                acc2[0] = (f32x4){0.f, 0.f, 0.f, 0.f};
                acc2[1] = (f32x4){0.f, 0.f, 0.f, 0.f};
                #pragma unroll
                for (int kiter = 0; kiter < 4; ++kiter) {
                    short8 af = *(const short8*)(&sm.f.Ash[rt * 16 + l15][kiter * 32 + quad * 8]);
                    const int cswz = (kiter * 4 + quad) ^ l15;
                    #pragma unroll
                    for (int cc = 0; cc < 2; ++cc) {
                        int ct = cp * 2 + cc;
                        short8 bf = *(const short8*)(&sm.f.Wsh[((ct * 16 + l15) << 4) | cswz]);
                        acc2[cc] = __builtin_amdgcn_mfma_f32_16x16x32_bf16(af, bf, acc2[cc], 0, 0, 0);
                    }
                }
                const int rbase = blk0 + rt * 16 + quad * 4;
                if (pl) {
                    int gr[4];
                    #pragma unroll
                    for (int r = 0; r < 4; ++r)
                        gr[r] = (rbase + r < p.N) ? p.batch[rbase + r] : -1;
                    #pragma unroll
                    for (int cc = 0; cc < 2; ++cc) {
                        int colc = (cp * 2 + cc) * 16 + l15;
                        float bcol = bias[colc];
                        float s = 0.f; int gprev = -2;
                        #pragma unroll
                        for (int r = 0; r < 4; ++r) {
                            if (gr[r] >= 0) {
                                float v = fmaxf(acc2[cc][r] + bcol, 0.f);
                                if (gr[r] == gprev) s += v;
                                else {
                                    if (gprev >= 0) atomicAdd(&pl[(size_t)gprev * 128 + colc], s);
                                    gprev = gr[r]; s = v;
                                }
                            }
                        }
                        if (gprev >= 0) atomicAdd(&pl[(size_t)gprev * 128 + colc], s);
                    }
                } else {
                    float ds[4];
                    #pragma unroll
                    for (int r = 0; r < 4; ++r) {
                        int rr = rbase + r;
                        ds[r] = (dscale && rr < p.N) ? dscale[rr] : 1.f;
                    }
                    #pragma unroll
                    for (int cc = 0; cc < 2; ++cc) {
                        int colc = (cp * 2 + cc) * 16 + l15;
                        float bcol = bias[colc];
                        #pragma unroll
                        for (int r = 0; r < 4; ++r) {
                            int rr = rbase + r;
                            if (rr < p.N) {
                                float v = fmaxf(acc2[cc][r] + bcol, 0.f) * ds[r];
                                Cd[(size_t)rr * 128 + colc] = f2bf(v);
                            }
                        }
                    }
                }
            }
            gg.sync();
        }
    }

    // ================= phase 6: head =================
    if (blockIdx.x < (p.G + 15) / 16) {
        const int g0 = blockIdx.x * 16;
        const int lane = t & 63, wv = t >> 6;
        const int l15 = lane & 15, quad = lane >> 4;

        if (t < 256) {
            for (int i = t; i < 16 * 256; i += 256) {
                int g = i >> 8, k = i & 255;
                sm.h.A[g][k] = f2bf(p.mol[(size_t)(g0 + g) * 256 + k]);
            }
            for (int i = t; i < 16 * 128; i += 256) {
                int g = i >> 7, k = i & 127;
                float c = p.cnt[g0 + g];
                sm.h.Mn[g][k] = f2bf(p.pool[(size_t)(g0 + g) * 128 + k] / fmaxf(c, 1.f));
            }
        }
        __syncthreads();

        auto do_tile = [&](const unsigned short* actb, int astr, int K,
                           const unsigned short* W, int orow,
                           const float* __restrict__ bias, int bidx,
                           unsigned short* dstb, int dstr, int ocol, bool dorelu) {
            f32x4 c = {0.f, 0.f, 0.f, 0.f};
            for (int kt = 0; kt < (K >> 5); ++kt) {
                short8 af = *(const short8*)(actb + (size_t)l15 * astr + kt * 32 + quad * 8);
                short8 bf = *(const short8*)(W + (size_t)orow * K + kt * 32 + quad * 8);
                c = __builtin_amdgcn_mfma_f32_16x16x32_bf16(af, bf, c, 0, 0, 0);
            }
            float bb = bias[bidx];
            #pragma unroll
            for (int r = 0; r < 4; ++r) {
                int g = quad * 4 + r;
                float v = c[r] + bb;
                if (dorelu) v = fmaxf(v, 0.f);
                dstb[(size_t)g * dstr + ocol] = f2bf(v);
            }
        };

        if (t < 256) {
            #pragma unroll
            for (int nt = 0; nt < 4; ++nt) {
                int o = (wv * 4 + nt) * 16 + l15;
                do_tile(&sm.h.A[0][0], 264, 256, p.Wh + HW_MLP0, o, p.mlpb, o, &sm.h.Bs[0][0], 264, o, true);
            }
        }
        __syncthreads();
        if (t < 256) {
            #pragma unroll
            for (int nt = 0; nt < 4; ++nt) {
                int o = (wv * 4 + nt) * 16 + l15;
                do_tile(&sm.h.Bs[0][0], 264, 256, p.Wh + HW_MLP1, o, p.mlpb + 256, o, &sm.h.A[0][0], 264, o, true);
            }
        }
        __syncthreads();
        if (t < 256) {
            #pragma unroll
            for (int j = 0; j < 3; ++j) {
                int tile = wv * 3 + j;
                if (tile < 8) {
                    int o = tile * 16 + l15;
                    do_tile(&sm.h.Mn[0][0], 136, 128, p.Wh + HW_GCNO, o, p.gcnob, o, &sm.h.Cc[0][0], 200, o, false);
                } else {
                    int om = (tile - 8) * 16 + l15;
                    do_tile(&sm.h.A[0][0], 264, 256, p.Wh + HW_MLO, om, p.mlob, om, &sm.h.Cc[0][0], 200, 128 + om, true);
                }
            }
        }
        __syncthreads();
        if (t < 256) {
            #pragma unroll
            for (int nt = 0; nt < 4; ++nt) {
                int o = (wv * 4 + nt) * 16 + l15;
                do_tile(&sm.h.Cc[0][0], 200, 192, p.Wh + HW_PW1, o, p.pb1, o, &sm.h.Bs[0][0], 264, o, true);
            }
        }
        __syncthreads();
        if (t < 256) {
            float pacc[4] = {0.f, 0.f, 0.f, 0.f};
            #pragma unroll
            for (int nt = 0; nt < 4; ++nt) {
                int o = (wv * 4 + nt) * 16 + l15;
                f32x4 c = {0.f, 0.f, 0.f, 0.f};
                #pragma unroll
                for (int kt = 0; kt < 8; ++kt) {
                    short8 af = *(const short8*)(&sm.h.Bs[0][0] + (size_t)l15 * 264 + kt * 32 + quad * 8);
                    short8 bf = *(const short8*)(p.Wh + HW_PW2 + (size_t)o * 256 + kt * 32 + quad * 8);
                    c = __builtin_amdgcn_mfma_f32_16x16x32_bf16(af, bf, c, 0, 0, 0);
                }
                float bb = p.pb2[o], wo = p.oW[o];
                #pragma unroll
                for (int r = 0; r < 4; ++r)
                    pacc[r] += fmaxf(c[r] + bb, 0.f) * wo;
            }
            #pragma unroll
            for (int off = 1; off < 16; off <<= 1)
                #pragma unroll
                for (int r = 0; r < 4; ++r)
                    pacc[r] += __shfl_xor(pacc[r], off, 64);
            if (l15 == 0) {
                #pragma unroll
                for (int r = 0; r < 4; ++r)
                    sm.h.red[wv][quad * 4 + r] = pacc[r];
            }
        }
        __syncthreads();
        if (t < 16) {
            float s = sm.h.red[0][t] + sm.h.red[1][t] + sm.h.red[2][t] + sm.h.red[3][t] + p.ob[0];
            if (g0 + t < p.G) p.out[g0 + t] = s;
        }
    }
}

extern "C" void kernel_launch(void* const* d_in, const int* in_sizes, int n_in,
                              void* d_out, int out_size, void* d_ws, size_t ws_size,
                              hipStream_t stream) {
    const float* x     = (const float*)d_in[0];
    const int*   ei    = (const int*)d_in[1];
    const int*   batch = (const int*)d_in[2];
    const float* mol   = (const float*)d_in[3];
    const float* gcnW  = (const float*)d_in[4];
    const float* gcnb  = (const float*)d_in[5];
    const float* gcnoW = (const float*)d_in[6];
    const float* gcnob = (const float*)d_in[7];
    const float* mlpW  = (const float*)d_in[8];
    const float* mlpb  = (const float*)d_in[9];
    const float* mloW  = (const float*)d_in[10];
    const float* mlob  = (const float*)d_in[11];
    const float* pW1   = (const float*)d_in[12];
    const float* pb1   = (const float*)d_in[13];
    const float* pW2   = (const float*)d_in[14];
    const float* pb2   = (const float*)d_in[15];
    const float* oW    = (const float*)d_in[16];
    const float* ob    = (const float*)d_in[17];

    const int N = in_sizes[0] / 128;
    const int E = in_sizes[1] / 2;
    const int G = in_sizes[3] / 256;
    const int* row = ei;
    const int* col = ei + E;

    const int NBK = (N + BKT - 1) / BKT;       // 782 buckets
    const int M = NBK * SL;                    // 12512 cells

    char* p = (char*)d_ws;
    auto alloc = [&](size_t bytes) {
        char* q = p;
        p += (bytes + 255) & ~(size_t)255;
        return (void*)q;
    };
    int*    rs    = (int*)alloc((size_t)NBK * 64 * 4);
    unsigned short* rd = (unsigned short*)alloc((size_t)NBK * 64 * 2);
    float*  dinv  = (float*)alloc((size_t)NBK * 64 * 4);
    int*    cur   = (int*)alloc((size_t)M * 16 * 4);   // line-padded cursors
    unsigned* gbin = (unsigned*)alloc((size_t)M * CAP * 4);
    unsigned short* csrf = (unsigned short*)alloc(((size_t)NBK * WCAP + 32) * 2);
    unsigned short* xb   = (unsigned short*)alloc((size_t)HROWS * 128 * 2);
    unsigned short* bufA = (unsigned short*)alloc((size_t)HROWS * 128 * 2);
    unsigned short* bufB = (unsigned short*)alloc((size_t)HROWS * 128 * 2);
    uint4*  Wb    = (uint4*)alloc((size_t)3 * 2048 * 16);
    unsigned short* Wh = (unsigned short*)alloc((size_t)HW_TOT * 2);
    float*  pool  = (float*)alloc((size_t)G * 128 * 4);
    float*  cnt   = (float*)alloc((size_t)G * 4);

    MegaParams mp;
    mp.cur = cur; mp.pool = pool; mp.cnt = cnt;
    mp.gcnW = gcnW; mp.Wb = Wb;
    mp.mlpW = mlpW; mp.mloW = mloW; mp.gcnoW = gcnoW;
    mp.pW1 = pW1; mp.pW2 = pW2; mp.Wh = Wh;
    mp.xb = xb; mp.bufA = bufA; mp.bufB = bufB;
    mp.batch = batch; mp.row = row; mp.col = col;
    mp.gbin = gbin;
    mp.rs = rs; mp.rd = rd; mp.dinv = dinv; mp.csrf = csrf;
    mp.x = x; mp.gcnb = gcnb;
    mp.mol = mol; mp.mlpb = mlpb; mp.mlob = mlob; mp.gcnob = gcnob;
    mp.pb1 = pb1; mp.pb2 = pb2; mp.oW = oW; mp.ob = ob;
    mp.out = (float*)d_out;
    mp.M = M; mp.G = G; mp.N = N; mp.E = E; mp.NBK = NBK;

    int perCU = 0;
    hipOccupancyMaxActiveBlocksPerMultiprocessor(&perCU, k_mega, 1024, 0);
    if (perCU < 1) perCU = 1;
    int nb = perCU * 256;
    if (nb > 512) nb = 512;

    void* args[] = { &mp };
    hipLaunchCooperativeKernel((void*)k_mega, dim3(nb), dim3(1024), args, 0, stream);
}

// Round 12
// 338.874 us; speedup vs baseline: 1.6964x; 1.6964x over previous
//
#include <hip/hip_runtime.h>

// ---------------------------------------------------------------------------
// GCN model, re-associated: per layer h = relu((A_hat @ h_prev) @ W^T + b);
// pool BEFORE gcn_out linear. Node features BF16 (fp32 accumulate), dinv
// folded into features. CSR via single-pass padded-region binning.
// R1-R10: see ledger. Key: R3's wave-per-node 16-edge masked gather ran
//   47us; all subgroup-per-node variants (R7/R9/R10) sticky at 55-56us.
//   8-wide subgroup gathers spill (R6/R8). LDS-ids null (R9). L2 window
//   sort null (R10).
// R11: cooperative mega-kernel FAILED: shared worst-case regalloc spilled
//   the gather (WRITE 163MB scratch); abandoned.
// R12: R9 pipeline (pool fused into l=2, cnt binary-search, ping-pong,
//   7 dispatches) + R3's PROVEN gather loop (1 wave = 1 node, 16 edges per
//   batch, shfl id distribution, masked loads clamped to L1-hot row 0).
//   Ish staging dropped (null). k_csr unchanged (x8 pad inert for masked
//   loop).
// ---------------------------------------------------------------------------

typedef __attribute__((ext_vector_type(8))) short short8;   // MFMA A/B frag
typedef __attribute__((ext_vector_type(4))) float f32x4;    // MFMA C/D frag

#define BKT 64        // nodes per bucket
#define SL 16         // slices per bucket
#define CAP 192       // capacity per (bucket,slice) cell   (Poisson 64)
#define WCAP 2560     // csrf window per bucket (padded degs; Poisson 1024)
#define NBINBLK 2048  // k_bin grid
#define HROWS 65536   // h-buffer rows allocated (row N = dummy zero row)

// Head-weight bf16 arena offsets (elements)
#define HW_MLP0 0
#define HW_MLP1 65536
#define HW_MLO  131072
#define HW_GCNO 147456
#define HW_PW1  163840
#define HW_PW2  212992
#define HW_TOT  278528

__device__ __forceinline__ unsigned short f2bf(float f) {
    union { float f; unsigned u; } c; c.f = f;
    unsigned u = c.u;
    unsigned r = u + 0x7FFFu + ((u >> 16) & 1u);   // RNE
    return (unsigned short)(r >> 16);
}
__device__ __forceinline__ float bflo(unsigned w) {
    union { unsigned u; float f; } c; c.u = w << 16; return c.f;
}
__device__ __forceinline__ float bfhi(unsigned w) {
    union { unsigned u; float f; } c; c.u = w & 0xFFFF0000u; return c.f;
}

// zero line-padded cursors, pool, dummy rows; cnt[g] via binary search on
// sorted batch (no atomics); cast gcn_W -> swizzled bf16; cast ALL head
// weights -> flat bf16 arena Wh.
__global__ void k_init(int* cur, float* pool, float* cnt,
                       const float* __restrict__ gcnW, uint4* __restrict__ Wb,
                       const float* __restrict__ mlpW, const float* __restrict__ mloW,
                       const float* __restrict__ gcnoW, const float* __restrict__ pW1,
                       const float* __restrict__ pW2, unsigned short* __restrict__ Wh,
                       unsigned short* xb, unsigned short* bufA, unsigned short* bufB,
                       const int* __restrict__ batch, int M, int G, int N) {
    int i = blockIdx.x * 256 + threadIdx.x;
    if (i < M * 16) cur[i] = 0;
    if (i < G * 128) pool[i] = 0.f;
    if (i < G) {
        // cnt[i] = #nodes with batch==i (batch sorted ascending)
        int lo = 0, hi = N;
        while (lo < hi) { int m = (lo + hi) >> 1; if (batch[m] < i) lo = m + 1; else hi = m; }
        int lo2 = lo, hi2 = N;
        while (lo2 < hi2) { int m = (lo2 + hi2) >> 1; if (batch[m] < i + 1) lo2 = m + 1; else hi2 = m; }
        cnt[i] = (float)(lo2 - lo);
    }
    if (i < 192) {                       // zero dummy row N of the 3 h-buffers
        unsigned short* b = (i < 64) ? xb : (i < 128) ? bufA : bufB;
        *(unsigned*)(b + (size_t)N * 128 + (i & 63) * 2) = 0u;
    }
    if (i < 3 * 2048) {                  // gcn W cast: chunk c=k/8, row o, layer l
        int l = i >> 11, rem = i & 2047;
        int o = rem >> 4, c = rem & 15;
        const float4* s = (const float4*)(gcnW + (size_t)l * 16384 + o * 128 + c * 8);
        float4 a = s[0], b = s[1];
        uint4 v;
        v.x = ((unsigned)f2bf(a.y) << 16) | f2bf(a.x);
        v.y = ((unsigned)f2bf(a.w) << 16) | f2bf(a.z);
        v.z = ((unsigned)f2bf(b.y) << 16) | f2bf(b.x);
        v.w = ((unsigned)f2bf(b.w) << 16) | f2bf(b.z);
        Wb[(l << 11) | (o << 4) | (c ^ (o & 15))] = v;
    }
    int j = i - 8192;                    // head-weight flat cast, 8 elems/thread
    if (j >= 0 && j < (HW_TOT / 8)) {
        int e = j * 8;
        const float* src;
        if (e < HW_MLO)        src = mlpW  + e;
        else if (e < HW_GCNO)  src = mloW  + (e - HW_MLO);
        else if (e < HW_PW1)   src = gcnoW + (e - HW_GCNO);
        else if (e < HW_PW2)   src = pW1   + (e - HW_PW1);
        else                   src = pW2   + (e - HW_PW2);
        float4 a = *(const float4*)src;
        float4 b = *((const float4*)src + 1);
        uint4 v;
        v.x = ((unsigned)f2bf(a.y) << 16) | f2bf(a.x);
        v.y = ((unsigned)f2bf(a.w) << 16) | f2bf(a.z);
        v.z = ((unsigned)f2bf(b.y) << 16) | f2bf(b.x);
        v.w = ((unsigned)f2bf(b.w) << 16) | f2bf(b.z);
        *(uint4*)(Wh + e) = v;
    }
}

// Single-pass binning. Cursor cell = cur[cell*16] (one 64B line per cell);
// gbin position = cell*CAP + count (closed form).
__global__ __launch_bounds__(256) void k_bin(const int* __restrict__ row,
                                             const int* __restrict__ col,
                                             int* __restrict__ cur,
                                             unsigned* __restrict__ gbin,
                                             int E, int C) {
    const int x = blockIdx.x & (SL - 1);
    int e0 = blockIdx.x * C, e1 = min(E, e0 + C);
    for (int e = e0 + threadIdx.x; e < e1; e += 256) {
        int c = col[e];
        int cell = (c >> 6) * SL + x;
        int cnt = atomicAdd(&cur[cell << 4], 1);
        gbin[cell * CAP + cnt] = (unsigned)row[e] | ((unsigned)(c & 63) << 16);
    }
}

// One block per bucket: LDS histogram of 64 dsts -> (start,deg,dinv) with
// degs PADDED to x8 in the prefix scan; scatter 2B src ids; fill pad slots
// with dummy src N; fused x->bf16*dinv cast.
__global__ __launch_bounds__(256) void k_csr(const unsigned* __restrict__ gbin,
                                             const int* __restrict__ cur,
                                             int* __restrict__ rs,
                                             unsigned short* __restrict__ rd,
                                             float* __restrict__ dinv,
                                             unsigned short* __restrict__ csrf,
                                             const float* __restrict__ x,
                                             unsigned short* __restrict__ xb,
                                             int N) {
    const int b = blockIdx.x, t = threadIdx.x;
    __shared__ int hcnt[64], lcur[64], fills[SL];
    __shared__ float sdinv[64];
    if (t < 64) hcnt[t] = 0;
    if (t < SL) fills[t] = cur[(b * SL + t) << 4];
    __syncthreads();
    #pragma unroll 4
    for (int xx = 0; xx < SL; ++xx) {
        int cbase = (b * SL + xx) * CAP, fill = fills[xx];
        for (int i = t; i < fill; i += 256)
            atomicAdd(&hcnt[(gbin[cbase + i] >> 16) & 63], 1);
    }
    __syncthreads();
    if (t < 64) {
        int v = hcnt[t];
        int vp = (v + 7) & ~7;          // padded degree
        int xs = vp;
        #pragma unroll
        for (int off = 1; off < 64; off <<= 1) {
            int u = __shfl_up(xs, off, 64);
            if (t >= off) xs += u;
        }
        int excl = xs - vp;             // padded exclusive prefix (x8 aligned)
        lcur[t] = excl;
        float d = rsqrtf((float)v + 1.0f);
        sdinv[t] = d;
        int node = b * 64 + t;          // rs/rd/dinv sized NBK*64: always safe
        rs[node] = b * WCAP + excl;
        rd[node] = (unsigned short)v;
        dinv[node] = d;
    }
    __syncthreads();
    #pragma unroll 4
    for (int xx = 0; xx < SL; ++xx) {
        int cbase = (b * SL + xx) * CAP, fill = fills[xx];
        for (int i = t; i < fill; i += 256) {
            unsigned v = gbin[cbase + i];
            int p = atomicAdd(&lcur[(v >> 16) & 63], 1);
            csrf[b * WCAP + p] = (unsigned short)(v & 0xFFFFu);
        }
    }
    __syncthreads();
    if (t < 64) {                        // fill pad slots with dummy src N
        int v = hcnt[t], vp = (v + 7) & ~7;
        int base = lcur[t];              // == excl + v after scatter
        for (int p = v; p < vp; ++p)
            csrf[b * WCAP + base + (p - v)] = (unsigned short)N;
    }
    // fused x -> bf16*dinv cast (64 nodes x 16 chunks)
    const int node0 = b * 64;
    #pragma unroll
    for (int it = 0; it < 4; ++it) {
        int i = t + it * 256;              // 0..1023
        int nd = node0 + (i >> 4);
        if (nd < N) {
            int ch = i & 15;
            float d = sdinv[i >> 4];
            const float4* s = (const float4*)(x + (size_t)nd * 128 + ch * 8);
            float4 a = s[0], bb = s[1];
            uint4 o;
            o.x = ((unsigned)f2bf(d * a.y) << 16) | f2bf(d * a.x);
            o.y = ((unsigned)f2bf(d * a.w) << 16) | f2bf(d * a.z);
            o.z = ((unsigned)f2bf(d * bb.y) << 16) | f2bf(d * bb.x);
            o.w = ((unsigned)f2bf(d * bb.w) << 16) | f2bf(d * bb.z);
            *(uint4*)(xb + (size_t)nd * 128 + ch * 8) = o;
        }
    }
}

// Fused per-layer kernel: block = 64 nodes = one MFMA tile, 1024 thr, 16
// waves, 2 blocks/CU. Gather = R3's proven loop: wave wv handles nodes
// wv*4..wv*4+3 serially; 16 edges per batch (csrf ushort per lane, shfl
// distribution); masked lanes clamp src -> L1-hot row 0; 16-group shfl_xor
// reduce; slot==0 lanes add self-row, scale by dinv, pack bf16 into Ash.
// MFMA: wave = (row-tile rt, col-pair cp); C = relu(A @ W^T + b) * dscale.
// l=2 (pool != nullptr): skip C store, atomic segment-sum into pool.
// h (input) and C (output) MUST be distinct buffers (launcher ping-pongs).
__global__ __launch_bounds__(1024, 8) void k_fused(
    const unsigned short* __restrict__ h,
    const uint4* __restrict__ Wb,
    const float* __restrict__ bias,
    const float* __restrict__ dscale,
    const float* __restrict__ dinv,
    const int* __restrict__ rs,
    const unsigned short* __restrict__ rd,
    const unsigned short* __restrict__ csrf,
    unsigned short* __restrict__ C,
    const int* __restrict__ batch,
    float* __restrict__ pool, int N) {
    __shared__ uint4 Wsh[2048];                 // 32 KB swizzled weights
    __shared__ unsigned short Ash[64][136];     // 17 KB padded A tile

    const int t = threadIdx.x;
    Wsh[t] = Wb[t];
    Wsh[t + 1024] = Wb[t + 1024];

    const int lane = t & 63;
    const int wv = t >> 6;                      // 0..15
    const int fg = lane & 15;
    const int slot = lane >> 4;
    const int blk0 = blockIdx.x * 64;

    // ---- gather phase (R3): 4 nodes per wave, 16 edges per batch ----
    for (int s = 0; s < 4; ++s) {
        const int lrow = wv * 4 + s;
        const int n = blk0 + lrow;
        if (n < N) {
            const int st = rs[n], e = st + rd[n];
            float acc[8] = {0.f, 0.f, 0.f, 0.f, 0.f, 0.f, 0.f, 0.f};
            for (int base = st; base < e; base += 16) {
                int src_l = csrf[base + fg];           // padded window: in-bounds
                #pragma unroll
                for (int i = 0; i < 4; ++i) {
                    int j = i * 4 + slot;
                    bool ok = (base + j) < e;          // mask value AND address
                    int src = __shfl(src_l, j, 16);
                    src = ok ? src : 0;                // masked lanes -> hot row 0
                    uint4 v = *(const uint4*)(h + (size_t)src * 128 + fg * 8);
                    v.x = ok ? v.x : 0u; v.y = ok ? v.y : 0u;
                    v.z = ok ? v.z : 0u; v.w = ok ? v.w : 0u;
                    acc[0] += bflo(v.x); acc[1] += bfhi(v.x);
                    acc[2] += bflo(v.y); acc[3] += bfhi(v.y);
                    acc[4] += bflo(v.z); acc[5] += bfhi(v.z);
                    acc[6] += bflo(v.w); acc[7] += bfhi(v.w);
                }
            }
            #pragma unroll
            for (int r = 0; r < 8; ++r) {
                acc[r] += __shfl_xor(acc[r], 16, 64);
                acc[r] += __shfl_xor(acc[r], 32, 64);
            }
            if (slot == 0) {
                float dn = dinv[n];
                uint4 hv = *(const uint4*)(h + (size_t)n * 128 + fg * 8);
                float sv[8] = {bflo(hv.x), bfhi(hv.x), bflo(hv.y), bfhi(hv.y),
                               bflo(hv.z), bfhi(hv.z), bflo(hv.w), bfhi(hv.w)};
                unsigned short ob[8];
                #pragma unroll
                for (int r = 0; r < 8; ++r) ob[r] = f2bf(dn * (acc[r] + sv[r]));
                uint4 o;
                o.x = ((unsigned)ob[1] << 16) | ob[0];
                o.y = ((unsigned)ob[3] << 16) | ob[2];
                o.z = ((unsigned)ob[5] << 16) | ob[4];
                o.w = ((unsigned)ob[7] << 16) | ob[6];
                *(uint4*)(&Ash[lrow][fg * 8]) = o;
            }
        } else if (slot == 0) {
            uint4 z = {0u, 0u, 0u, 0u};
            *(uint4*)(&Ash[lrow][fg * 8]) = z;
        }
    }
    __syncthreads();

    // ---- MFMA ----
    const int l15 = fg, quad = slot;
    const int rt = wv & 3, cp = wv >> 2;
    f32x4 acc2[2];
    acc2[0] = (f32x4){0.f, 0.f, 0.f, 0.f};
    acc2[1] = (f32x4){0.f, 0.f, 0.f, 0.f};
    #pragma unroll
    for (int kiter = 0; kiter < 4; ++kiter) {
        short8 af = *(const short8*)(&Ash[rt * 16 + l15][kiter * 32 + quad * 8]);
        const int cswz = (kiter * 4 + quad) ^ l15;
        #pragma unroll
        for (int cc = 0; cc < 2; ++cc) {
            int ct = cp * 2 + cc;
            short8 bf = *(const short8*)(&Wsh[((ct * 16 + l15) << 4) | cswz]);
            acc2[cc] = __builtin_amdgcn_mfma_f32_16x16x32_bf16(af, bf, acc2[cc], 0, 0, 0);
        }
    }

    const int rbase = blk0 + rt * 16 + quad * 4;
    if (pool) {
        // l=2: relu + segment-sum into pool (rows sorted by graph)
        int gr[4];
        #pragma unroll
        for (int r = 0; r < 4; ++r)
            gr[r] = (rbase + r < N) ? batch[rbase + r] : -1;
        #pragma unroll
        for (int cc = 0; cc < 2; ++cc) {
            int colc = (cp * 2 + cc) * 16 + l15;
            float bcol = bias[colc];
            float s = 0.f; int gprev = -2;
            #pragma unroll
            for (int r = 0; r < 4; ++r) {
                if (gr[r] >= 0) {
                    float v = fmaxf(acc2[cc][r] + bcol, 0.f);
                    if (gr[r] == gprev) s += v;
                    else {
                        if (gprev >= 0) atomicAdd(&pool[(size_t)gprev * 128 + colc], s);
                        gprev = gr[r]; s = v;
                    }
                }
            }
            if (gprev >= 0) atomicAdd(&pool[(size_t)gprev * 128 + colc], s);
        }
    } else {
        float ds[4];
        #pragma unroll
        for (int r = 0; r < 4; ++r) {
            int rr = rbase + r;
            ds[r] = (dscale && rr < N) ? dscale[rr] : 1.f;
        }
        #pragma unroll
        for (int cc = 0; cc < 2; ++cc) {
            int colc = (cp * 2 + cc) * 16 + l15;
            float bcol = bias[colc];
            #pragma unroll
            for (int r = 0; r < 4; ++r) {
                int rr = rbase + r;
                if (rr < N) {
                    float v = fmaxf(acc2[cc][r] + bcol, 0.f) * ds[r];
                    C[(size_t)rr * 128 + colc] = f2bf(v);
                }
            }
        }
    }
}

// Fused head via MFMA: 16 graphs/block (M=16), 256 thr = 4 waves. Activations
// bf16 in LDS; B-frags from bf16 weight arena in global (L2-hot). Each wave
// owns 4 of 16 output-tiles per 256-out layer. fp32 accumulation throughout.
__global__ __launch_bounds__(256) void k_head(
    const unsigned short* __restrict__ Wh,
    const float* __restrict__ pool, const float* __restrict__ cnt,
    const float* __restrict__ mol,
    const float* __restrict__ mlpb, const float* __restrict__ mlob,
    const float* __restrict__ gcnob,
    const float* __restrict__ pb1, const float* __restrict__ pb2,
    const float* __restrict__ oW, const float* __restrict__ ob,
    float* __restrict__ out, int G) {
    const int g0 = blockIdx.x * 16;
    const int t = threadIdx.x;
    const int lane = t & 63, wv = t >> 6;
    const int l15 = lane & 15, quad = lane >> 4;
    __shared__ unsigned short A[16][264], B[16][264], Cc[16][200], Mn[16][136];
    __shared__ float red[4][16];

    for (int i = t; i < 16 * 256; i += 256) {
        int g = i >> 8, k = i & 255;
        A[g][k] = f2bf(mol[(size_t)(g0 + g) * 256 + k]);
    }
    for (int i = t; i < 16 * 128; i += 256) {
        int g = i >> 7, k = i & 127;
        float c = cnt[g0 + g];
        Mn[g][k] = f2bf(pool[(size_t)(g0 + g) * 128 + k] / fmaxf(c, 1.f));
    }
    __syncthreads();

    // one 16x16 output tile: rows=graphs, cols=ocol..ocol+15 (lane col=l15)
    auto do_tile = [&](const unsigned short* actb, int astr, int K,
                       const unsigned short* W, int orow,
                       const float* __restrict__ bias, int bidx,
                       unsigned short* dstb, int dstr, int ocol, bool dorelu) {
        f32x4 c = {0.f, 0.f, 0.f, 0.f};
        for (int kt = 0; kt < (K >> 5); ++kt) {
            short8 af = *(const short8*)(actb + (size_t)l15 * astr + kt * 32 + quad * 8);
            short8 bf = *(const short8*)(W + (size_t)orow * K + kt * 32 + quad * 8);
            c = __builtin_amdgcn_mfma_f32_16x16x32_bf16(af, bf, c, 0, 0, 0);
        }
        float bb = bias[bidx];
        #pragma unroll
        for (int r = 0; r < 4; ++r) {
            int g = quad * 4 + r;
            float v = c[r] + bb;
            if (dorelu) v = fmaxf(v, 0.f);
            dstb[(size_t)g * dstr + ocol] = f2bf(v);
        }
    };

    // mlp0: A(K=256) -> B relu
    #pragma unroll
    for (int nt = 0; nt < 4; ++nt) {
        int o = (wv * 4 + nt) * 16 + l15;
        do_tile(&A[0][0], 264, 256, Wh + HW_MLP0, o, mlpb, o, &B[0][0], 264, o, true);
    }
    __syncthreads();
    // mlp1: B(K=256) -> A relu
    #pragma unroll
    for (int nt = 0; nt < 4; ++nt) {
        int o = (wv * 4 + nt) * 16 + l15;
        do_tile(&B[0][0], 264, 256, Wh + HW_MLP1, o, mlpb + 256, o, &A[0][0], 264, o, true);
    }
    __syncthreads();
    // concat -> Cc[16][192]: tiles 0..7 gcn_out (K=128 from Mn, no relu),
    // tiles 8..11 mlo (K=256 from A, relu, cols 128..191). Wave w: tiles 3w..3w+2.
    #pragma unroll
    for (int j = 0; j < 3; ++j) {
        int tile = wv * 3 + j;
        if (tile < 8) {
            int o = tile * 16 + l15;
            do_tile(&Mn[0][0], 136, 128, Wh + HW_GCNO, o, gcnob, o, &Cc[0][0], 200, o, false);
        } else {
            int om = (tile - 8) * 16 + l15;
            do_tile(&A[0][0], 264, 256, Wh + HW_MLO, om, mlob, om, &Cc[0][0], 200, 128 + om, true);
        }
    }
    __syncthreads();
    // pred1: Cc(K=192) -> B relu
    #pragma unroll
    for (int nt = 0; nt < 4; ++nt) {
        int o = (wv * 4 + nt) * 16 + l15;
        do_tile(&Cc[0][0], 200, 192, Wh + HW_PW1, o, pb1, o, &B[0][0], 264, o, true);
    }
    __syncthreads();
    // pred2 (K=256) fused with out-dot
    {
        float pacc[4] = {0.f, 0.f, 0.f, 0.f};
        #pragma unroll
        for (int nt = 0; nt < 4; ++nt) {
            int o = (wv * 4 + nt) * 16 + l15;
            f32x4 c = {0.f, 0.f, 0.f, 0.f};
            #pragma unroll
            for (int kt = 0; kt < 8; ++kt) {
                short8 af = *(const short8*)(&B[0][0] + (size_t)l15 * 264 + kt * 32 + quad * 8);
                short8 bf = *(const short8*)(Wh + HW_PW2 + (size_t)o * 256 + kt * 32 + quad * 8);
                c = __builtin_amdgcn_mfma_f32_16x16x32_bf16(af, bf, c, 0, 0, 0);
            }
            float bb = pb2[o], wo = oW[o];
            #pragma unroll
            for (int r = 0; r < 4; ++r)
                pacc[r] += fmaxf(c[r] + bb, 0.f) * wo;
        }
        // reduce over l15 (16 lanes within quad)
        #pragma unroll
        for (int off = 1; off < 16; off <<= 1)
            #pragma unroll
            for (int r = 0; r < 4; ++r)
                pacc[r] += __shfl_xor(pacc[r], off, 64);
        if (l15 == 0) {
            #pragma unroll
            for (int r = 0; r < 4; ++r)
                red[wv][quad * 4 + r] = pacc[r];
        }
    }
    __syncthreads();
    if (t < 16) {
        float s = red[0][t] + red[1][t] + red[2][t] + red[3][t] + ob[0];
        if (g0 + t < G) out[g0 + t] = s;
    }
}

extern "C" void kernel_launch(void* const* d_in, const int* in_sizes, int n_in,
                              void* d_out, int out_size, void* d_ws, size_t ws_size,
                              hipStream_t stream) {
    const float* x     = (const float*)d_in[0];
    const int*   ei    = (const int*)d_in[1];
    const int*   batch = (const int*)d_in[2];
    const float* mol   = (const float*)d_in[3];
    const float* gcnW  = (const float*)d_in[4];
    const float* gcnb  = (const float*)d_in[5];
    const float* gcnoW = (const float*)d_in[6];
    const float* gcnob = (const float*)d_in[7];
    const float* mlpW  = (const float*)d_in[8];
    const float* mlpb  = (const float*)d_in[9];
    const float* mloW  = (const float*)d_in[10];
    const float* mlob  = (const float*)d_in[11];
    const float* pW1   = (const float*)d_in[12];
    const float* pb1   = (const float*)d_in[13];
    const float* pW2   = (const float*)d_in[14];
    const float* pb2   = (const float*)d_in[15];
    const float* oW    = (const float*)d_in[16];
    const float* ob    = (const float*)d_in[17];

    const int N = in_sizes[0] / 128;
    const int E = in_sizes[1] / 2;
    const int G = in_sizes[3] / 256;
    const int* row = ei;
    const int* col = ei + E;

    const int NBK = (N + BKT - 1) / BKT;       // 782 buckets
    const int M = NBK * SL;                    // 12512 cells
    const int C = (E + NBINBLK - 1) / NBINBLK; // edges per bin block

    char* p = (char*)d_ws;
    auto alloc = [&](size_t bytes) {
        char* q = p;
        p += (bytes + 255) & ~(size_t)255;
        return (void*)q;
    };
    int*    rs    = (int*)alloc((size_t)NBK * 64 * 4);
    unsigned short* rd = (unsigned short*)alloc((size_t)NBK * 64 * 2);
    float*  dinv  = (float*)alloc((size_t)NBK * 64 * 4);
    int*    cur   = (int*)alloc((size_t)M * 16 * 4);   // line-padded cursors
    unsigned* gbin = (unsigned*)alloc((size_t)M * CAP * 4);
    unsigned short* csrf = (unsigned short*)alloc(((size_t)NBK * WCAP + 32) * 2);
    unsigned short* xb   = (unsigned short*)alloc((size_t)HROWS * 128 * 2);
    unsigned short* bufA = (unsigned short*)alloc((size_t)HROWS * 128 * 2);
    unsigned short* bufB = (unsigned short*)alloc((size_t)HROWS * 128 * 2);
    uint4*  Wb    = (uint4*)alloc((size_t)3 * 2048 * 16);
    unsigned short* Wh = (unsigned short*)alloc((size_t)HW_TOT * 2);
    float*  pool  = (float*)alloc((size_t)G * 128 * 4);
    float*  cnt   = (float*)alloc((size_t)G * 4);

    const int initblocks = (M * 16 + 255) / 256;   // covers cursors + casts

    k_init<<<initblocks, 256, 0, stream>>>(cur, pool, cnt, gcnW, Wb,
                                           mlpW, mloW, gcnoW, pW1, pW2, Wh,
                                           xb, bufA, bufB, batch, M, G, N);
    k_bin<<<NBINBLK, 256, 0, stream>>>(row, col, cur, gbin, E, C);
    k_csr<<<NBK, 256, 0, stream>>>(gbin, cur, rs, rd, dinv, csrf, x, xb, N);

    const int fblocks = (N + 63) / 64;
    // ping-pong: xb -> bufA -> bufB -> (pool)  (src and dst always distinct)
    k_fused<<<fblocks, 1024, 0, stream>>>(xb, Wb, gcnb, dinv, dinv,
                                          rs, rd, csrf, bufA,
                                          batch, (float*)nullptr, N);
    k_fused<<<fblocks, 1024, 0, stream>>>(bufA, Wb + 2048, gcnb + 128, dinv, dinv,
                                          rs, rd, csrf, bufB,
                                          batch, (float*)nullptr, N);
    k_fused<<<fblocks, 1024, 0, stream>>>(bufB, Wb + 4096, gcnb + 256,
                                          (const float*)nullptr, dinv,
                                          rs, rd, csrf, bufA,
                                          batch, pool, N);
    k_head<<<(G + 15) / 16, 256, 0, stream>>>(
        Wh, pool, cnt, mol, mlpb, mlob, gcnob, pb1, pb2, oW, ob,
        (float*)d_out, G);
}